// Round 1
// baseline (983.863 us; speedup 1.0000x reference)
//
#include <hip/hip_runtime.h>
#include <hip/hip_bf16.h>

#define Hh 256
#define Ii 128
#define KF 384    // 128 (x) + 256 (hx) feature dim
#define LDSB 72   // padded LDS stride (bf16 elems)

typedef __attribute__((ext_vector_type(8))) short bf16x8;
typedef __attribute__((ext_vector_type(4))) float f32x4;
typedef unsigned short u16;
typedef unsigned int u32;

__device__ inline u16 f2bf(float f) {
  u32 u = __float_as_uint(f);
  u += 0x7FFFu + ((u >> 16) & 1u);   // RNE
  return (u16)(u >> 16);
}
__device__ inline u32 pack_bf16x2(float a, float b) {
  __hip_bfloat162 h = __float22bfloat162_rn(make_float2(a, b));
  u32 r; __builtin_memcpy(&r, &h, 4); return r;
}
// scale packed bf16 pair by (va, vb), repack
__device__ inline u32 scale2(u32 packed, float va, float vb) {
  float lo = __uint_as_float(packed << 16) * va;
  float hi = __uint_as_float(packed & 0xFFFF0000u) * vb;
  return pack_bf16x2(lo, hi);
}
__device__ inline float sigm(float x) { return 1.0f / (1.0f + __expf(-x)); }
__device__ inline float tanh_f(float x) { return 1.0f - 2.0f / (1.0f + __expf(2.0f * x)); }

union U32x4 { bf16x8 f; u32 d[4]; uint4 v; };

// ---------------- kernel 0: pack weights, transpose Vtinv, pack Uinv --------
__global__ __launch_bounds__(256) void k_prep(
    const float* __restrict__ Wii, const float* __restrict__ Wif, const float* __restrict__ Wig,
    const float* __restrict__ Whi, const float* __restrict__ Whit,
    const float* __restrict__ Whf, const float* __restrict__ Whft,
    const float* __restrict__ Whc, const float* __restrict__ Whct,
    const float* __restrict__ Vtinv, const float* __restrict__ Uinv,
    u16* __restrict__ RW, u16* __restrict__ CW, u16* __restrict__ Vtt,
    float* __restrict__ UinvP, float* __restrict__ proj) {
  const int tid = threadIdx.x, bx = blockIdx.x, y = blockIdx.y;
  if (y < 3) {
    const float* WX  = (y == 0) ? Wii : (y == 1 ? Wif : Wig);
    const float* WHr = (y == 0) ? Whi : (y == 1 ? Whf : Whc);
    const float* WHt = (y == 0) ? Whit : (y == 1 ? Whft : Whct);
    u16* rw = RW + y * Hh * KF;
    u16* cw = CW + y * Hh * KF;
#pragma unroll
    for (int it = 0; it < 4; ++it) {
      int idx = it * 24576 + bx * 256 + tid;   // 0..98303
      int h = idx / KF, t = idx - h * KF;
      float a, c;
      if (t < Ii) { a = WX[h * Ii + t]; c = a; }
      else        { a = WHr[h * Hh + t - Ii]; c = WHt[h * Hh + t - Ii]; }
      rw[idx] = f2bf(a);
      cw[idx] = f2bf(c);
    }
  } else if (y == 3) {
    if (bx < 64) {
      // Vtt[i][k] = Vtinv[k][i], 32x32 LDS tile transpose
      __shared__ u16 tbuf[32][33];
      const int c = tid & 31, r8 = tid >> 5;
      const int tr = bx >> 3, tc = bx & 7;
#pragma unroll
      for (int rr = r8; rr < 32; rr += 8)
        tbuf[rr][c] = f2bf(Vtinv[(tc * 32 + rr) * Hh + tr * 32 + c]);
      __syncthreads();
#pragma unroll
      for (int rr = r8; rr < 32; rr += 8)
        Vtt[(tr * 32 + rr) * Hh + tc * 32 + c] = tbuf[c][rr];
    } else if (bx < 96) {
      const int base = (bx - 64) * 256 + tid;
      const float4 z = {0.f, 0.f, 0.f, 0.f};
#pragma unroll
      for (int it = 0; it < 4; ++it)
        *(float4*)(proj + (size_t)(it * 8192 + base) * 4) = z;
    }
  } else {
    // UinvP: f = tid512*128 + e ; e = ti*32 + tjl*4 + r
    if (bx < 32) {
      const int base = (bx * 256 + tid) * 8;
#pragma unroll
      for (int e8 = 0; e8 < 8; ++e8) {
        int f = base + e8;                  // 0..65535
        int t512 = f >> 7;
        int e = f & 127;
        int ti = e >> 5;
        int rem = e & 31;
        int tjl = rem >> 2;
        int rr = rem & 3;
        int wv = t512 >> 6;
        int ln = t512 & 63;
        int qd = ln >> 4;
        int r15v = ln & 15;
        int i = (wv & 3) * 64 + ti * 16 + qd * 4 + rr;
        int j = (wv >> 2) * 128 + tjl * 16 + r15v;
        UinvP[f] = Uinv[i * Hh + j];
      }
    }
  }
}

// ---------------- kernel 1: fused gates + cell + down-projection -------------
// grid 2048 = b(512) x kb(4); 512 threads = 8 waves; wave owns 32 j-rows.
// Scaled-B (CW rows * v) staged ONCE per (b,kb) in LDS dbuf; RW j-row frags
// raw from global (L2-hot). MFMA operands: A = scaled CW k-rows (LDS),
// B = RW j-rows -> C has k along quad*4+r, j along r15 => float4 bias/cx
// loads and contiguous packed sP stores.
__global__ __launch_bounds__(512, 4) void k_main(
    const float* __restrict__ x, const float* __restrict__ hx, const float* __restrict__ cx,
    const u16* __restrict__ RW, const u16* __restrict__ CW, const u16* __restrict__ Vtt,
    const float* __restrict__ bi, const float* __restrict__ bfm, const float* __restrict__ bg,
    const float* __restrict__ UinvP, float* __restrict__ proj) {
  __shared__ u16 sB[2 * 64 * LDSB];    // 18432 B dbuf scaled-B (64 k-rows x 64 t)
  __shared__ u16 sP[256 * LDSB];       // 36864 B c-tile (256 j x 64 k)
  __shared__ float sV[KF];             //  1536 B
  __shared__ float sPart[8][64];       //  2048 B projection partials

  const int tid  = threadIdx.x;
  const int b    = blockIdx.x >> 2;
  const int kb   = blockIdx.x & 3;
  const int k0   = kb * 64;
  const int lane = tid & 63;
  const int w    = tid >> 6;
  const int r15  = lane & 15;
  const int quad = lane >> 4;
  const int brow = tid >> 3, bcg = tid & 7;

  if (tid < Ii) sV[tid] = x[b * Ii + tid];
  if (tid < Hh) sV[Ii + tid] = hx[b * Hh + tid];

  // phase order: g (tanh), i, f
  const u16* rwp[3] = {RW + 2 * Hh * KF, RW, RW + 1 * Hh * KF};
  const u16* cwp[3] = {CW + 2 * Hh * KF, CW, CW + 1 * Hh * KF};
  const float* bp3[3] = {bg, bi, bfm};
  const float* cx_b = cx + (size_t)b * Hh * Hh;

  // prologue: raw chunk 0 load (independent of sV)
  U32x4 m;
  m.v = *(const uint4*)(cwp[0] + (size_t)(k0 + brow) * KF + bcg * 8);
  __syncthreads();   // sV ready
  {
    U32x4 o;
    const float4 va = *(const float4*)(&sV[bcg * 8]);
    const float4 vb = *(const float4*)(&sV[bcg * 8 + 4]);
    o.d[0] = scale2(m.d[0], va.x, va.y); o.d[1] = scale2(m.d[1], va.z, va.w);
    o.d[2] = scale2(m.d[2], vb.x, vb.y); o.d[3] = scale2(m.d[3], vb.z, vb.w);
    *(uint4*)(&sB[brow * LDSB + bcg * 8]) = o.v;
  }
  __syncthreads();   // sB[0] ready

  float p[2][4][4];
  const size_t wrow = (size_t)(w * 32 + r15) * KF;

#pragma unroll
  for (int ph = 0; ph < 3; ++ph) {
    f32x4 acc[2][4];
#pragma unroll
    for (int ja = 0; ja < 2; ++ja)
#pragma unroll
      for (int tk = 0; tk < 4; ++tk)
#pragma unroll
        for (int r = 0; r < 4; ++r) acc[ja][tk][r] = 0.0f;

#pragma unroll
    for (int kc = 0; kc < 6; ++kc) {
      const int sc  = ph * 6 + kc;
      const int cur = sc & 1;
      const int t0  = kc * 64;
      const int nph = (kc < 5) ? ph : (ph < 2 ? ph + 1 : 0);
      const int nt0 = (kc < 5) ? t0 + 64 : 0;
      U32x4 mn;
      if (sc < 17)
        mn.v = *(const uint4*)(cwp[nph] + (size_t)(k0 + brow) * KF + nt0 + bcg * 8);
      bf16x8 wf[2][2];
#pragma unroll
      for (int ja = 0; ja < 2; ++ja)
#pragma unroll
        for (int ks = 0; ks < 2; ++ks)
          wf[ja][ks] = *(const bf16x8*)(rwp[ph] + wrow + (size_t)ja * 16 * KF + t0 + ks * 32 + quad * 8);
#pragma unroll
      for (int ks = 0; ks < 2; ++ks) {
        bf16x8 sf[4];
#pragma unroll
        for (int tk = 0; tk < 4; ++tk)
          sf[tk] = *(const bf16x8*)(&sB[cur * (64 * LDSB) + (tk * 16 + r15) * LDSB + ks * 32 + quad * 8]);
#pragma unroll
        for (int tk = 0; tk < 4; ++tk) {
          acc[0][tk] = __builtin_amdgcn_mfma_f32_16x16x32_bf16(sf[tk], wf[0][ks], acc[0][tk], 0, 0, 0);
          acc[1][tk] = __builtin_amdgcn_mfma_f32_16x16x32_bf16(sf[tk], wf[1][ks], acc[1][tk], 0, 0, 0);
        }
      }
      if (sc < 17) {
        U32x4 o;
        const float4 va = *(const float4*)(&sV[nt0 + bcg * 8]);
        const float4 vb = *(const float4*)(&sV[nt0 + bcg * 8 + 4]);
        o.d[0] = scale2(mn.d[0], va.x, va.y); o.d[1] = scale2(mn.d[1], va.z, va.w);
        o.d[2] = scale2(mn.d[2], vb.x, vb.y); o.d[3] = scale2(mn.d[3], vb.z, vb.w);
        *(uint4*)(&sB[(cur ^ 1) * (64 * LDSB) + brow * LDSB + bcg * 8]) = o.v;
      }
      if (kc == 5) {
        // C layout: row(k) = k0 + tk*16 + quad*4 + r, col(j) = w*32 + ja*16 + r15
        const float* bp = bp3[ph];
#pragma unroll
        for (int ja = 0; ja < 2; ++ja) {
          const int jg = w * 32 + ja * 16 + r15;
          const float* bpr = bp + (size_t)jg * Hh + k0 + quad * 4;
          const float* cxr = cx_b + (size_t)jg * Hh + k0 + quad * 4;
#pragma unroll
          for (int tk = 0; tk < 4; ++tk) {
            const float4 bv = *(const float4*)(bpr + tk * 16);
            if (ph == 0) {
#pragma unroll
              for (int r = 0; r < 4; ++r)
                p[ja][tk][r] = tanh_f(acc[ja][tk][r] + ((const float*)&bv)[r]);
            } else if (ph == 1) {
#pragma unroll
              for (int r = 0; r < 4; ++r)
                p[ja][tk][r] *= sigm(acc[ja][tk][r] + ((const float*)&bv)[r]);
            } else {
              const float4 cv = *(const float4*)(cxr + tk * 16);
              float cc[4];
#pragma unroll
              for (int r = 0; r < 4; ++r)
                cc[r] = sigm(acc[ja][tk][r] + ((const float*)&bv)[r]) * ((const float*)&cv)[r] + p[ja][tk][r];
              uint2 pk;
              pk.x = pack_bf16x2(cc[0], cc[1]);
              pk.y = pack_bf16x2(cc[2], cc[3]);
              *(uint2*)(&sP[jg * LDSB + tk * 16 + quad * 4]) = pk;
            }
          }
        }
      }
      __syncthreads();
    }
  }

  // ---- projection: M[i,j] = sum_k Vtt[i,k] c[j,k]; racc[i] += M[i,j]*Uinv[i,j]
  //      wave: i-slab = (w&3)*64, j-half = (w>>2)*128 .. +128
  const int islab = (w & 3) * 64;
  const int jhb   = (w >> 2) * 128;
  const float* up = UinvP + (size_t)tid * 128;
  float racc[4][4];
#pragma unroll
  for (int ti = 0; ti < 4; ++ti)
#pragma unroll
    for (int r = 0; r < 4; ++r) racc[ti][r] = 0.0f;

#pragma unroll
  for (int tjg = 0; tjg < 2; ++tjg) {
    bf16x8 fbp[2][4];
#pragma unroll
    for (int ks = 0; ks < 2; ++ks)
#pragma unroll
      for (int tjj = 0; tjj < 4; ++tjj)
        fbp[ks][tjj] = *(const bf16x8*)(&sP[(jhb + (tjg * 4 + tjj) * 16 + r15) * LDSB + ks * 32 + quad * 8]);
#pragma unroll
    for (int ti = 0; ti < 4; ++ti) {
      const u16* vrow = Vtt + (size_t)(islab + ti * 16 + r15) * Hh + k0 + quad * 8;
      const bf16x8 va0 = *(const bf16x8*)vrow;
      const bf16x8 va1 = *(const bf16x8*)(vrow + 32);
      f32x4 pacc[4];
#pragma unroll
      for (int tjj = 0; tjj < 4; ++tjj)
#pragma unroll
        for (int r = 0; r < 4; ++r) pacc[tjj][r] = 0.0f;
#pragma unroll
      for (int tjj = 0; tjj < 4; ++tjj)
        pacc[tjj] = __builtin_amdgcn_mfma_f32_16x16x32_bf16(va0, fbp[0][tjj], pacc[tjj], 0, 0, 0);
#pragma unroll
      for (int tjj = 0; tjj < 4; ++tjj)
        pacc[tjj] = __builtin_amdgcn_mfma_f32_16x16x32_bf16(va1, fbp[1][tjj], pacc[tjj], 0, 0, 0);
#pragma unroll
      for (int tjj = 0; tjj < 4; ++tjj) {
        const float4 uu = *(const float4*)(up + ti * 32 + (tjg * 4 + tjj) * 4);
#pragma unroll
        for (int r = 0; r < 4; ++r)
          racc[ti][r] += pacc[tjj][r] * ((const float*)&uu)[r];
      }
    }
  }

#pragma unroll
  for (int ti = 0; ti < 4; ++ti)
#pragma unroll
    for (int r = 0; r < 4; ++r) {
      float v = racc[ti][r];
      v += __shfl_xor(v, 1);
      v += __shfl_xor(v, 2);
      v += __shfl_xor(v, 4);
      v += __shfl_xor(v, 8);
      if (r15 == 0) sPart[w][ti * 16 + quad * 4 + r] = v;
    }
  __syncthreads();
  if (tid < Hh)
    atomicAdd(&proj[b * Hh + tid], sPart[tid >> 6][tid & 63] + sPart[(tid >> 6) + 4][tid & 63]);
}

// ---------------- kernel 2: o-gate + final output ---------------------------
__global__ __launch_bounds__(256) void k_out(
    const float* __restrict__ x, const float* __restrict__ hx,
    const float* __restrict__ Wio, const float* __restrict__ Who,
    const float* __restrict__ bo, const float* __restrict__ proj,
    float* __restrict__ out) {
  __shared__ float sv[KF];
  const int b = blockIdx.x, tid = threadIdx.x;
  const int lane = tid & 63, w = tid >> 6;
  if (tid < Ii) sv[tid] = x[b * Ii + tid];
  sv[Ii + tid] = hx[b * Hh + tid];
  __syncthreads();
  for (int rr = 0; rr < 64; ++rr) {
    const int h = w * 64 + rr;
    float p = Wio[h * Ii + lane]        * sv[lane]
            + Wio[h * Ii + 64 + lane]   * sv[64 + lane]
            + Who[h * Hh + lane]        * sv[128 + lane]
            + Who[h * Hh + 64 + lane]   * sv[192 + lane]
            + Who[h * Hh + 128 + lane]  * sv[256 + lane]
            + Who[h * Hh + 192 + lane]  * sv[320 + lane];
    p += __shfl_xor(p, 32);
    p += __shfl_xor(p, 16);
    p += __shfl_xor(p, 8);
    p += __shfl_xor(p, 4);
    p += __shfl_xor(p, 2);
    p += __shfl_xor(p, 1);
    if (lane == 0)
      out[b * Hh + h] = sigm(p + bo[h]) * sigm(proj[b * Hh + h]);
  }
}

extern "C" void kernel_launch(void* const* d_in, const int* in_sizes, int n_in,
                              void* d_out, int out_size, void* d_ws, size_t ws_size,
                              hipStream_t stream) {
  (void)in_sizes; (void)n_in; (void)out_size; (void)ws_size;
  const float* x    = (const float*)d_in[0];
  const float* hx   = (const float*)d_in[1];
  const float* cx   = (const float*)d_in[2];
  const float* Wii  = (const float*)d_in[3];
  const float* Wif  = (const float*)d_in[4];
  const float* Wig  = (const float*)d_in[5];
  const float* Wio  = (const float*)d_in[6];
  const float* Whi  = (const float*)d_in[7];
  const float* Whit = (const float*)d_in[8];
  const float* Whf  = (const float*)d_in[9];
  const float* Whft = (const float*)d_in[10];
  const float* Whc  = (const float*)d_in[11];
  const float* Whct = (const float*)d_in[12];
  const float* Who  = (const float*)d_in[13];
  const float* Uinv = (const float*)d_in[14];
  const float* Vtinv= (const float*)d_in[15];
  const float* bi   = (const float*)d_in[16];
  const float* bf   = (const float*)d_in[17];
  const float* bg   = (const float*)d_in[18];
  const float* bo   = (const float*)d_in[19];
  float* out = (float*)d_out;

  // workspace (~2.0 MB): RW[3], CW[3], Vtt (bf16); UinvP, proj (f32)
  u16* RW    = (u16*)d_ws;
  u16* CW    = RW + 3 * Hh * KF;
  u16* Vtt   = CW + 3 * Hh * KF;
  float* UinvP = (float*)(Vtt + Hh * Hh);
  float* proj  = UinvP + Hh * Hh;

  k_prep<<<dim3(96, 5), 256, 0, stream>>>(Wii, Wif, Wig, Whi, Whit, Whf, Whft, Whc, Whct,
                                          Vtinv, Uinv, RW, CW, Vtt, UinvP, proj);
  k_main<<<2048, 512, 0, stream>>>(x, hx, cx, RW, CW, Vtt, bi, bf, bg, UinvP, proj);
  k_out<<<512, 256, 0, stream>>>(x, hx, Wio, Who, bo, proj, out);
}

// Round 2
// 583.414 us; speedup vs baseline: 1.6864x; 1.6864x over previous
//
#include <hip/hip_runtime.h>
#include <hip/hip_bf16.h>

#define Hh 256
#define Ii 128
#define KF 384    // 128 (x) + 256 (hx) feature dim
#define LDSB 72   // padded LDS stride (bf16 elems)

typedef __attribute__((ext_vector_type(8))) short bf16x8;
typedef __attribute__((ext_vector_type(4))) float f32x4;
typedef unsigned short u16;
typedef unsigned int u32;

__device__ inline u16 f2bf(float f) {
  u32 u = __float_as_uint(f);
  u += 0x7FFFu + ((u >> 16) & 1u);   // RNE
  return (u16)(u >> 16);
}
__device__ inline u32 pack_bf16x2(float a, float b) {
  __hip_bfloat162 h = __float22bfloat162_rn(make_float2(a, b));
  u32 r; __builtin_memcpy(&r, &h, 4); return r;
}
// scale packed bf16 pair by (va, vb), repack
__device__ inline u32 scale2(u32 packed, float va, float vb) {
  float lo = __uint_as_float(packed << 16) * va;
  float hi = __uint_as_float(packed & 0xFFFF0000u) * vb;
  return pack_bf16x2(lo, hi);
}
__device__ inline float sigm(float x) { return 1.0f / (1.0f + __expf(-x)); }
__device__ inline float tanh_f(float x) { return 1.0f - 2.0f / (1.0f + __expf(2.0f * x)); }

union U32x4 { bf16x8 f; u32 d[4]; uint4 v; };

// ---------------- kernel 0: pack weights, transpose Vtinv, pack Uinv --------
__global__ __launch_bounds__(256) void k_prep(
    const float* __restrict__ Wii, const float* __restrict__ Wif, const float* __restrict__ Wig,
    const float* __restrict__ Whi, const float* __restrict__ Whit,
    const float* __restrict__ Whf, const float* __restrict__ Whft,
    const float* __restrict__ Whc, const float* __restrict__ Whct,
    const float* __restrict__ Vtinv, const float* __restrict__ Uinv,
    u16* __restrict__ RW, u16* __restrict__ CW, u16* __restrict__ Vtt,
    float* __restrict__ UinvP, float* __restrict__ proj) {
  const int tid = threadIdx.x, bx = blockIdx.x, y = blockIdx.y;
  if (y < 3) {
    const float* WX  = (y == 0) ? Wii : (y == 1 ? Wif : Wig);
    const float* WHr = (y == 0) ? Whi : (y == 1 ? Whf : Whc);
    const float* WHt = (y == 0) ? Whit : (y == 1 ? Whft : Whct);
    u16* rw = RW + y * Hh * KF;
    u16* cw = CW + y * Hh * KF;
#pragma unroll
    for (int it = 0; it < 4; ++it) {
      int idx = it * 24576 + bx * 256 + tid;   // 0..98303
      int h = idx / KF, t = idx - h * KF;
      float a, c;
      if (t < Ii) { a = WX[h * Ii + t]; c = a; }
      else        { a = WHr[h * Hh + t - Ii]; c = WHt[h * Hh + t - Ii]; }
      rw[idx] = f2bf(a);
      cw[idx] = f2bf(c);
    }
  } else if (y == 3) {
    if (bx < 64) {
      // Vtt[i][k] = Vtinv[k][i], 32x32 LDS tile transpose
      __shared__ u16 tbuf[32][33];
      const int c = tid & 31, r8 = tid >> 5;
      const int tr = bx >> 3, tc = bx & 7;
#pragma unroll
      for (int rr = r8; rr < 32; rr += 8)
        tbuf[rr][c] = f2bf(Vtinv[(tc * 32 + rr) * Hh + tr * 32 + c]);
      __syncthreads();
#pragma unroll
      for (int rr = r8; rr < 32; rr += 8)
        Vtt[(tr * 32 + rr) * Hh + tc * 32 + c] = tbuf[c][rr];
    } else if (bx < 96) {
      const int base = (bx - 64) * 256 + tid;
      const float4 z = {0.f, 0.f, 0.f, 0.f};
#pragma unroll
      for (int it = 0; it < 4; ++it)
        *(float4*)(proj + (size_t)(it * 8192 + base) * 4) = z;
    }
  } else {
    // UinvP: f = tid512*128 + e ; e = ti*32 + tjl*4 + r
    if (bx < 32) {
      const int base = (bx * 256 + tid) * 8;
#pragma unroll
      for (int e8 = 0; e8 < 8; ++e8) {
        int f = base + e8;                  // 0..65535
        int t512 = f >> 7;
        int e = f & 127;
        int ti = e >> 5;
        int rem = e & 31;
        int tjl = rem >> 2;
        int rr = rem & 3;
        int wv = t512 >> 6;
        int ln = t512 & 63;
        int qd = ln >> 4;
        int r15v = ln & 15;
        int i = (wv & 3) * 64 + ti * 16 + qd * 4 + rr;
        int j = (wv >> 2) * 128 + tjl * 16 + r15v;
        UinvP[f] = Uinv[i * Hh + j];
      }
    }
  }
}

// ---------------- kernel 1: fused gates + cell + down-projection -------------
// grid 2048 = b(512) x kb(4); 512 threads = 8 waves; wave owns 32 j-rows.
// Scaled-B (CW rows * v) staged ONCE per (b,kb) in LDS dbuf; RW j-row frags
// raw from global (L2-hot). MFMA operands: A = scaled CW k-rows (LDS),
// B = RW j-rows -> C has k along quad*4+r, j along r15 => float4 bias/cx
// loads and contiguous packed sP stores.
// NOTE: no min-waves launch_bounds arg — (512,4) capped VGPRs at 64 and
// spilled ~2.2 GB of scratch traffic/dispatch (R1). LDS (58.9 KB) already
// limits occupancy to 2 blocks/CU = 4 waves/SIMD, which allows 512 VGPRs.
__global__ __launch_bounds__(512) void k_main(
    const float* __restrict__ x, const float* __restrict__ hx, const float* __restrict__ cx,
    const u16* __restrict__ RW, const u16* __restrict__ CW, const u16* __restrict__ Vtt,
    const float* __restrict__ bi, const float* __restrict__ bfm, const float* __restrict__ bg,
    const float* __restrict__ UinvP, float* __restrict__ proj) {
  __shared__ u16 sB[2 * 64 * LDSB];    // 18432 B dbuf scaled-B (64 k-rows x 64 t)
  __shared__ u16 sP[256 * LDSB];       // 36864 B c-tile (256 j x 64 k)
  __shared__ float sV[KF];             //  1536 B
  __shared__ float sPart[8][64];       //  2048 B projection partials

  const int tid  = threadIdx.x;
  const int b    = blockIdx.x >> 2;
  const int kb   = blockIdx.x & 3;
  const int k0   = kb * 64;
  const int lane = tid & 63;
  const int w    = tid >> 6;
  const int r15  = lane & 15;
  const int quad = lane >> 4;
  const int brow = tid >> 3, bcg = tid & 7;

  if (tid < Ii) sV[tid] = x[b * Ii + tid];
  if (tid < Hh) sV[Ii + tid] = hx[b * Hh + tid];

  // phase order: g (tanh), i, f
  const u16* rwp[3] = {RW + 2 * Hh * KF, RW, RW + 1 * Hh * KF};
  const u16* cwp[3] = {CW + 2 * Hh * KF, CW, CW + 1 * Hh * KF};
  const float* bp3[3] = {bg, bi, bfm};
  const float* cx_b = cx + (size_t)b * Hh * Hh;

  // prologue: raw chunk 0 load (independent of sV)
  U32x4 m;
  m.v = *(const uint4*)(cwp[0] + (size_t)(k0 + brow) * KF + bcg * 8);
  __syncthreads();   // sV ready
  {
    U32x4 o;
    const float4 va = *(const float4*)(&sV[bcg * 8]);
    const float4 vb = *(const float4*)(&sV[bcg * 8 + 4]);
    o.d[0] = scale2(m.d[0], va.x, va.y); o.d[1] = scale2(m.d[1], va.z, va.w);
    o.d[2] = scale2(m.d[2], vb.x, vb.y); o.d[3] = scale2(m.d[3], vb.z, vb.w);
    *(uint4*)(&sB[brow * LDSB + bcg * 8]) = o.v;
  }
  __syncthreads();   // sB[0] ready

  float p[2][4][4];
  const size_t wrow = (size_t)(w * 32 + r15) * KF;

#pragma unroll
  for (int ph = 0; ph < 3; ++ph) {
    f32x4 acc[2][4];
#pragma unroll
    for (int ja = 0; ja < 2; ++ja)
#pragma unroll
      for (int tk = 0; tk < 4; ++tk)
#pragma unroll
        for (int r = 0; r < 4; ++r) acc[ja][tk][r] = 0.0f;

#pragma unroll
    for (int kc = 0; kc < 6; ++kc) {
      const int sc  = ph * 6 + kc;
      const int cur = sc & 1;
      const int t0  = kc * 64;
      const int nph = (kc < 5) ? ph : (ph < 2 ? ph + 1 : 0);
      const int nt0 = (kc < 5) ? t0 + 64 : 0;
      U32x4 mn;
      if (sc < 17)
        mn.v = *(const uint4*)(cwp[nph] + (size_t)(k0 + brow) * KF + nt0 + bcg * 8);
      bf16x8 wf[2][2];
#pragma unroll
      for (int ja = 0; ja < 2; ++ja)
#pragma unroll
        for (int ks = 0; ks < 2; ++ks)
          wf[ja][ks] = *(const bf16x8*)(rwp[ph] + wrow + (size_t)ja * 16 * KF + t0 + ks * 32 + quad * 8);
#pragma unroll
      for (int ks = 0; ks < 2; ++ks) {
        bf16x8 sf[4];
#pragma unroll
        for (int tk = 0; tk < 4; ++tk)
          sf[tk] = *(const bf16x8*)(&sB[cur * (64 * LDSB) + (tk * 16 + r15) * LDSB + ks * 32 + quad * 8]);
#pragma unroll
        for (int tk = 0; tk < 4; ++tk) {
          acc[0][tk] = __builtin_amdgcn_mfma_f32_16x16x32_bf16(sf[tk], wf[0][ks], acc[0][tk], 0, 0, 0);
          acc[1][tk] = __builtin_amdgcn_mfma_f32_16x16x32_bf16(sf[tk], wf[1][ks], acc[1][tk], 0, 0, 0);
        }
      }
      if (sc < 17) {
        U32x4 o;
        const float4 va = *(const float4*)(&sV[nt0 + bcg * 8]);
        const float4 vb = *(const float4*)(&sV[nt0 + bcg * 8 + 4]);
        o.d[0] = scale2(mn.d[0], va.x, va.y); o.d[1] = scale2(mn.d[1], va.z, va.w);
        o.d[2] = scale2(mn.d[2], vb.x, vb.y); o.d[3] = scale2(mn.d[3], vb.z, vb.w);
        *(uint4*)(&sB[(cur ^ 1) * (64 * LDSB) + brow * LDSB + bcg * 8]) = o.v;
      }
      if (kc == 5) {
        // C layout: row(k) = k0 + tk*16 + quad*4 + r, col(j) = w*32 + ja*16 + r15
        const float* bp = bp3[ph];
#pragma unroll
        for (int ja = 0; ja < 2; ++ja) {
          const int jg = w * 32 + ja * 16 + r15;
          const float* bpr = bp + (size_t)jg * Hh + k0 + quad * 4;
          const float* cxr = cx_b + (size_t)jg * Hh + k0 + quad * 4;
#pragma unroll
          for (int tk = 0; tk < 4; ++tk) {
            const float4 bv = *(const float4*)(bpr + tk * 16);
            if (ph == 0) {
#pragma unroll
              for (int r = 0; r < 4; ++r)
                p[ja][tk][r] = tanh_f(acc[ja][tk][r] + ((const float*)&bv)[r]);
            } else if (ph == 1) {
#pragma unroll
              for (int r = 0; r < 4; ++r)
                p[ja][tk][r] *= sigm(acc[ja][tk][r] + ((const float*)&bv)[r]);
            } else {
              const float4 cv = *(const float4*)(cxr + tk * 16);
              float cc[4];
#pragma unroll
              for (int r = 0; r < 4; ++r)
                cc[r] = sigm(acc[ja][tk][r] + ((const float*)&bv)[r]) * ((const float*)&cv)[r] + p[ja][tk][r];
              uint2 pk;
              pk.x = pack_bf16x2(cc[0], cc[1]);
              pk.y = pack_bf16x2(cc[2], cc[3]);
              *(uint2*)(&sP[jg * LDSB + tk * 16 + quad * 4]) = pk;
            }
          }
        }
      }
      __syncthreads();
    }
  }

  // ---- projection: M[i,j] = sum_k Vtt[i,k] c[j,k]; racc[i] += M[i,j]*Uinv[i,j]
  //      wave: i-slab = (w&3)*64, j-half = (w>>2)*128 .. +128
  const int islab = (w & 3) * 64;
  const int jhb   = (w >> 2) * 128;
  const float* up = UinvP + (size_t)tid * 128;
  float racc[4][4];
#pragma unroll
  for (int ti = 0; ti < 4; ++ti)
#pragma unroll
    for (int r = 0; r < 4; ++r) racc[ti][r] = 0.0f;

#pragma unroll
  for (int tjg = 0; tjg < 2; ++tjg) {
    bf16x8 fbp[2][4];
#pragma unroll
    for (int ks = 0; ks < 2; ++ks)
#pragma unroll
      for (int tjj = 0; tjj < 4; ++tjj)
        fbp[ks][tjj] = *(const bf16x8*)(&sP[(jhb + (tjg * 4 + tjj) * 16 + r15) * LDSB + ks * 32 + quad * 8]);
#pragma unroll
    for (int ti = 0; ti < 4; ++ti) {
      const u16* vrow = Vtt + (size_t)(islab + ti * 16 + r15) * Hh + k0 + quad * 8;
      const bf16x8 va0 = *(const bf16x8*)vrow;
      const bf16x8 va1 = *(const bf16x8*)(vrow + 32);
      f32x4 pacc[4];
#pragma unroll
      for (int tjj = 0; tjj < 4; ++tjj)
#pragma unroll
        for (int r = 0; r < 4; ++r) pacc[tjj][r] = 0.0f;
#pragma unroll
      for (int tjj = 0; tjj < 4; ++tjj)
        pacc[tjj] = __builtin_amdgcn_mfma_f32_16x16x32_bf16(va0, fbp[0][tjj], pacc[tjj], 0, 0, 0);
#pragma unroll
      for (int tjj = 0; tjj < 4; ++tjj)
        pacc[tjj] = __builtin_amdgcn_mfma_f32_16x16x32_bf16(va1, fbp[1][tjj], pacc[tjj], 0, 0, 0);
#pragma unroll
      for (int tjj = 0; tjj < 4; ++tjj) {
        const float4 uu = *(const float4*)(up + ti * 32 + (tjg * 4 + tjj) * 4);
#pragma unroll
        for (int r = 0; r < 4; ++r)
          racc[ti][r] += pacc[tjj][r] * ((const float*)&uu)[r];
      }
    }
  }

#pragma unroll
  for (int ti = 0; ti < 4; ++ti)
#pragma unroll
    for (int r = 0; r < 4; ++r) {
      float v = racc[ti][r];
      v += __shfl_xor(v, 1);
      v += __shfl_xor(v, 2);
      v += __shfl_xor(v, 4);
      v += __shfl_xor(v, 8);
      if (r15 == 0) sPart[w][ti * 16 + quad * 4 + r] = v;
    }
  __syncthreads();
  if (tid < Hh)
    atomicAdd(&proj[b * Hh + tid], sPart[tid >> 6][tid & 63] + sPart[(tid >> 6) + 4][tid & 63]);
}

// ---------------- kernel 2: o-gate + final output ---------------------------
__global__ __launch_bounds__(256) void k_out(
    const float* __restrict__ x, const float* __restrict__ hx,
    const float* __restrict__ Wio, const float* __restrict__ Who,
    const float* __restrict__ bo, const float* __restrict__ proj,
    float* __restrict__ out) {
  __shared__ float sv[KF];
  const int b = blockIdx.x, tid = threadIdx.x;
  const int lane = tid & 63, w = tid >> 6;
  if (tid < Ii) sv[tid] = x[b * Ii + tid];
  sv[Ii + tid] = hx[b * Hh + tid];
  __syncthreads();
  for (int rr = 0; rr < 64; ++rr) {
    const int h = w * 64 + rr;
    float p = Wio[h * Ii + lane]        * sv[lane]
            + Wio[h * Ii + 64 + lane]   * sv[64 + lane]
            + Who[h * Hh + lane]        * sv[128 + lane]
            + Who[h * Hh + 64 + lane]   * sv[192 + lane]
            + Who[h * Hh + 128 + lane]  * sv[256 + lane]
            + Who[h * Hh + 192 + lane]  * sv[320 + lane];
    p += __shfl_xor(p, 32);
    p += __shfl_xor(p, 16);
    p += __shfl_xor(p, 8);
    p += __shfl_xor(p, 4);
    p += __shfl_xor(p, 2);
    p += __shfl_xor(p, 1);
    if (lane == 0)
      out[b * Hh + h] = sigm(p + bo[h]) * sigm(proj[b * Hh + h]);
  }
}

extern "C" void kernel_launch(void* const* d_in, const int* in_sizes, int n_in,
                              void* d_out, int out_size, void* d_ws, size_t ws_size,
                              hipStream_t stream) {
  (void)in_sizes; (void)n_in; (void)out_size; (void)ws_size;
  const float* x    = (const float*)d_in[0];
  const float* hx   = (const float*)d_in[1];
  const float* cx   = (const float*)d_in[2];
  const float* Wii  = (const float*)d_in[3];
  const float* Wif  = (const float*)d_in[4];
  const float* Wig  = (const float*)d_in[5];
  const float* Wio  = (const float*)d_in[6];
  const float* Whi  = (const float*)d_in[7];
  const float* Whit = (const float*)d_in[8];
  const float* Whf  = (const float*)d_in[9];
  const float* Whft = (const float*)d_in[10];
  const float* Whc  = (const float*)d_in[11];
  const float* Whct = (const float*)d_in[12];
  const float* Who  = (const float*)d_in[13];
  const float* Uinv = (const float*)d_in[14];
  const float* Vtinv= (const float*)d_in[15];
  const float* bi   = (const float*)d_in[16];
  const float* bf   = (const float*)d_in[17];
  const float* bg   = (const float*)d_in[18];
  const float* bo   = (const float*)d_in[19];
  float* out = (float*)d_out;

  // workspace (~2.0 MB): RW[3], CW[3], Vtt (bf16); UinvP, proj (f32)
  u16* RW    = (u16*)d_ws;
  u16* CW    = RW + 3 * Hh * KF;
  u16* Vtt   = CW + 3 * Hh * KF;
  float* UinvP = (float*)(Vtt + Hh * Hh);
  float* proj  = UinvP + Hh * Hh;

  k_prep<<<dim3(96, 5), 256, 0, stream>>>(Wii, Wif, Wig, Whi, Whit, Whf, Whft, Whc, Whct,
                                          Vtinv, Uinv, RW, CW, Vtt, UinvP, proj);
  k_main<<<2048, 512, 0, stream>>>(x, hx, cx, RW, CW, Vtt, bi, bf, bg, UinvP, proj);
  k_out<<<512, 256, 0, stream>>>(x, hx, Wio, Who, bo, proj, out);
}